// Round 2
// baseline (53.588 us; speedup 1.0000x reference)
//
#include <hip/hip_runtime.h>

// Problem constants (RES = 64)
#define RES       64
#define CM1       63
#define NCELL     250047      // 63^3
#define NTET      1500282     // NCELL*6
#define V_ELEMS   27005076    // NTET*18  (v_pos: 6 edges * 3 coords per tet, float32)
#define TRI_ELEMS 9001692     // NTET*6   (2 tris * 3 idx per tet, stored as float32)
// valid: NTET*2 float32 elements follow tri

__constant__ int c_TETS[6][4] = {
    {0,5,1,6},{0,1,2,6},{0,2,3,6},{0,3,7,6},{0,7,4,6},{0,4,5,6}
};
__constant__ int c_OFF[8][3] = {
    {0,0,0},{1,0,0},{1,1,0},{0,1,0},{0,0,1},{1,0,1},{1,1,1},{0,1,1}
};
// TET_TRIS[16][2][3] flattened; -1 = invalid
__constant__ int c_TRI[16][6] = {
    {-1,-1,-1,-1,-1,-1},  // 0
    { 0, 3, 2,-1,-1,-1},  // 1
    { 0, 1, 4,-1,-1,-1},  // 2
    { 2, 3, 4, 2, 4, 1},  // 3
    { 1, 5, 2,-1,-1,-1},  // 4
    { 0, 1, 5, 0, 5, 3},  // 5
    { 0, 4, 5, 0, 5, 2},  // 6
    { 3, 4, 5,-1,-1,-1},  // 7
    { 3, 5, 4,-1,-1,-1},  // 8
    { 0, 2, 5, 0, 5, 4},  // 9
    { 0, 3, 5, 0, 5, 1},  // 10
    { 1, 2, 5,-1,-1,-1},  // 11
    { 1, 4, 3, 1, 3, 2},  // 12
    { 0, 4, 1,-1,-1,-1},  // 13
    { 0, 2, 3,-1,-1,-1},  // 14
    {-1,-1,-1,-1,-1,-1}   // 15
};

__global__ __launch_bounds__(256) void mc_kernel(const float* __restrict__ level,
                                                 float* __restrict__ out)
{
    int g = blockIdx.x * 256 + threadIdx.x;
    if (g >= NTET) return;

    int cell = g / 6;
    int tet  = g - cell * 6;
    int i    = cell / (CM1 * CM1);
    int rem  = cell - i * (CM1 * CM1);
    int j    = rem / CM1;
    int k    = rem - j * CM1;
    int base = i * (RES * RES) + j * RES + k;

    // Gather the 4 tet corners: f = -level, positions = (i,j,k)+offset
    float fv[4], px[4], py[4], pz[4];
    #pragma unroll
    for (int vi = 0; vi < 4; ++vi) {
        int c  = c_TETS[tet][vi];
        int ox = c_OFF[c][0], oy = c_OFF[c][1], oz = c_OFF[c][2];
        fv[vi] = -level[base + ox * (RES * RES) + oy * RES + oz];
        px[vi] = (float)(i + ox);
        py[vi] = (float)(j + oy);
        pz[vi] = (float)(k + oz);
    }

    int cs = (fv[0] > 0.0f ? 1 : 0) | (fv[1] > 0.0f ? 2 : 0)
           | (fv[2] > 0.0f ? 4 : 0) | (fv[3] > 0.0f ? 8 : 0);

    // Edge endpoint tables (compile-time after unroll)
    const int EA[6] = {0, 1, 2, 0, 1, 2};
    const int EB[6] = {1, 2, 0, 3, 3, 3};

    const float inv63 = 1.0f / 63.0f;
    float vbuf[18];
    #pragma unroll
    for (int e = 0; e < 6; ++e) {
        int a = EA[e], b = EB[e];
        float fa = fv[a], fb = fv[b];
        float d  = fa - fb;
        float ds = (fabsf(d) < 1e-8f) ? 1e-8f : d;
        float t  = fa / ds;                       // IEEE f32 divide, matches np
        t = fminf(fmaxf(t, 0.0f), 1.0f);
        float vx = px[a] + t * (px[b] - px[a]);
        float vy = py[a] + t * (py[b] - py[a]);
        float vz = pz[a] + t * (pz[b] - pz[a]);
        // reference reverses coord order: (z, y, x) / 63
        vbuf[e * 3 + 0] = vz * inv63;
        vbuf[e * 3 + 1] = vy * inv63;
        vbuf[e * 3 + 2] = vx * inv63;
    }

    // v_pos region: 18 f32 per tet at float offset g*18 (8B aligned -> float2 x9)
    float2* ov = (float2*)out;
    size_t vb2 = (size_t)g * 9;
    #pragma unroll
    for (int n = 0; n < 9; ++n)
        ov[vb2 + n] = make_float2(vbuf[2 * n], vbuf[2 * n + 1]);

    // tri + valid regions
    int base6 = g * 6;
    float tbuf[6];
    float valb[2];
    #pragma unroll
    for (int tr = 0; tr < 2; ++tr) {
        int t0 = c_TRI[cs][tr * 3 + 0];
        int t1 = c_TRI[cs][tr * 3 + 1];
        int t2 = c_TRI[cs][tr * 3 + 2];
        valb[tr] = (t0 >= 0) ? 1.0f : 0.0f;
        int m0 = t0 > 0 ? t0 : 0;
        int m1 = t1 > 0 ? t1 : 0;
        int m2 = t2 > 0 ? t2 : 0;
        tbuf[tr * 3 + 0] = (float)(base6 + m0); // < 2^24, exact in f32
        tbuf[tr * 3 + 1] = (float)(base6 + m1);
        tbuf[tr * 3 + 2] = (float)(base6 + m2);
    }

    float2* otri = (float2*)(out + V_ELEMS);   // byte offset 108,020,304 (8B aligned)
    size_t tb2 = (size_t)g * 3;
    otri[tb2 + 0] = make_float2(tbuf[0], tbuf[1]);
    otri[tb2 + 1] = make_float2(tbuf[2], tbuf[3]);
    otri[tb2 + 2] = make_float2(tbuf[4], tbuf[5]);

    float2* oval = (float2*)(out + V_ELEMS + TRI_ELEMS);
    oval[g] = make_float2(valb[0], valb[1]);
}

extern "C" void kernel_launch(void* const* d_in, const int* in_sizes, int n_in,
                              void* d_out, int out_size, void* d_ws, size_t ws_size,
                              hipStream_t stream) {
    const float* level = (const float*)d_in[0];
    float* out = (float*)d_out;
    int blocks = (NTET + 255) / 256;
    mc_kernel<<<blocks, 256, 0, stream>>>(level, out);
}

// Round 3
// 30.855 us; speedup vs baseline: 1.7368x; 1.7368x over previous
//
#include <hip/hip_runtime.h>

// Problem constants (RES = 64)
#define RES       64
#define CM1       63
#define NCELL     250047      // 63^3
#define NTET      1500282     // NCELL*6
#define V_ELEMS   27005076    // NTET*18  (v_pos: 6 edges * 3 coords per tet, float32)
#define TRI_ELEMS 9001692     // NTET*6   (2 tris * 3 idx per tet, stored as float32)
// valid: NTET*2 float32 elements follow tri

#define TPB 256

__constant__ int c_TETS[6][4] = {
    {0,5,1,6},{0,1,2,6},{0,2,3,6},{0,3,7,6},{0,7,4,6},{0,4,5,6}
};
__constant__ int c_OFF[8][3] = {
    {0,0,0},{1,0,0},{1,1,0},{0,1,0},{0,0,1},{1,0,1},{1,1,1},{0,1,1}
};
// TET_TRIS[16][2][3] flattened; -1 = invalid
__constant__ int c_TRI[16][6] = {
    {-1,-1,-1,-1,-1,-1},  // 0
    { 0, 3, 2,-1,-1,-1},  // 1
    { 0, 1, 4,-1,-1,-1},  // 2
    { 2, 3, 4, 2, 4, 1},  // 3
    { 1, 5, 2,-1,-1,-1},  // 4
    { 0, 1, 5, 0, 5, 3},  // 5
    { 0, 4, 5, 0, 5, 2},  // 6
    { 3, 4, 5,-1,-1,-1},  // 7
    { 3, 5, 4,-1,-1,-1},  // 8
    { 0, 2, 5, 0, 5, 4},  // 9
    { 0, 3, 5, 0, 5, 1},  // 10
    { 1, 2, 5,-1,-1,-1},  // 11
    { 1, 4, 3, 1, 3, 2},  // 12
    { 0, 4, 1,-1,-1,-1},  // 13
    { 0, 2, 3,-1,-1,-1},  // 14
    {-1,-1,-1,-1,-1,-1}   // 15
};

__global__ __launch_bounds__(TPB) void mc_kernel(const float* __restrict__ level,
                                                 float* __restrict__ out)
{
    // LDS staging buffers laid out exactly like the per-block global regions.
    __shared__ float sv[TPB * 18];  // v_pos   18 KiB
    __shared__ float st[TPB * 6];   // tri      6 KiB
    __shared__ float sl[TPB * 2];   // valid    2 KiB

    int t  = threadIdx.x;
    int g0 = blockIdx.x * TPB;
    int g  = g0 + t;
    int ntet = NTET - g0; if (ntet > TPB) ntet = TPB;   // 256, or 122 in the tail block

    if (t < ntet) {
        int cell = g / 6;
        int tet  = g - cell * 6;
        int i    = cell / (CM1 * CM1);
        int rem  = cell - i * (CM1 * CM1);
        int j    = rem / CM1;
        int k    = rem - j * CM1;
        int base = i * (RES * RES) + j * RES + k;

        // Gather the 4 tet corners: f = -level, positions = (i,j,k)+offset
        float fv[4], px[4], py[4], pz[4];
        #pragma unroll
        for (int vi = 0; vi < 4; ++vi) {
            int c  = c_TETS[tet][vi];
            int ox = c_OFF[c][0], oy = c_OFF[c][1], oz = c_OFF[c][2];
            fv[vi] = -level[base + ox * (RES * RES) + oy * RES + oz];
            px[vi] = (float)(i + ox);
            py[vi] = (float)(j + oy);
            pz[vi] = (float)(k + oz);
        }

        int cs = (fv[0] > 0.0f ? 1 : 0) | (fv[1] > 0.0f ? 2 : 0)
               | (fv[2] > 0.0f ? 4 : 0) | (fv[3] > 0.0f ? 8 : 0);

        const int EA[6] = {0, 1, 2, 0, 1, 2};
        const int EB[6] = {1, 2, 0, 3, 3, 3};

        const float inv63 = 1.0f / 63.0f;
        #pragma unroll
        for (int e = 0; e < 6; ++e) {
            int a = EA[e], b = EB[e];
            float fa = fv[a], fb = fv[b];
            float d  = fa - fb;
            float ds = (fabsf(d) < 1e-8f) ? 1e-8f : d;
            float tt = fa / ds;                       // IEEE f32 divide, matches np
            tt = fminf(fmaxf(tt, 0.0f), 1.0f);
            float vx = px[a] + tt * (px[b] - px[a]);
            float vy = py[a] + tt * (py[b] - py[a]);
            float vz = pz[a] + tt * (pz[b] - pz[a]);
            // reference reverses coord order: (z, y, x) / 63
            sv[t * 18 + e * 3 + 0] = vz * inv63;     // stride 18 -> 2-way bank alias (free)
            sv[t * 18 + e * 3 + 1] = vy * inv63;
            sv[t * 18 + e * 3 + 2] = vx * inv63;
        }

        int base6 = g * 6;
        #pragma unroll
        for (int tr = 0; tr < 2; ++tr) {
            int t0 = c_TRI[cs][tr * 3 + 0];
            int t1 = c_TRI[cs][tr * 3 + 1];
            int t2 = c_TRI[cs][tr * 3 + 2];
            sl[t * 2 + tr] = (t0 >= 0) ? 1.0f : 0.0f;
            int m0 = t0 > 0 ? t0 : 0;
            int m1 = t1 > 0 ? t1 : 0;
            int m2 = t2 > 0 ? t2 : 0;
            st[t * 6 + tr * 3 + 0] = (float)(base6 + m0);  // < 2^24, exact in f32
            st[t * 6 + tr * 3 + 1] = (float)(base6 + m1);
            st[t * 6 + tr * 3 + 2] = (float)(base6 + m2);
        }
    }

    __syncthreads();

    // Coalesced float4 copy-out. All counts divisible by 4 (ntet is even).
    {
        int n4 = (ntet * 18) >> 2;                       // 1152 (tail: 549)
        float4*       gv = (float4*)(out + (size_t)g0 * 18);
        const float4* lv = (const float4*)sv;
        for (int idx = t; idx < n4; idx += TPB) gv[idx] = lv[idx];
    }
    {
        int n4 = (ntet * 6) >> 2;                        // 384 (tail: 183)
        float4*       gt = (float4*)(out + V_ELEMS + (size_t)g0 * 6);
        const float4* lt = (const float4*)st;
        for (int idx = t; idx < n4; idx += TPB) gt[idx] = lt[idx];
    }
    {
        int n4 = (ntet * 2) >> 2;                        // 128 (tail: 61)
        float4*       gl = (float4*)(out + V_ELEMS + TRI_ELEMS + (size_t)g0 * 2);
        const float4* ll = (const float4*)sl;
        for (int idx = t; idx < n4; idx += TPB) gl[idx] = ll[idx];
    }
}

extern "C" void kernel_launch(void* const* d_in, const int* in_sizes, int n_in,
                              void* d_out, int out_size, void* d_ws, size_t ws_size,
                              hipStream_t stream) {
    const float* level = (const float*)d_in[0];
    float* out = (float*)d_out;
    int blocks = (NTET + TPB - 1) / TPB;
    mc_kernel<<<blocks, TPB, 0, stream>>>(level, out);
}